// Round 3
// 3446.111 us; speedup vs baseline: 1.1821x; 1.1821x over previous
//
#include <hip/hip_runtime.h>
#include <cstdint>

#define NE 100000   // edges
#define NA 5000     // atoms
#define DE 512      // edge feat
#define DAH 128     // atom feat
#define DT 64       // T
#define NS 7
#define KM 10
#define DR 16
#define INV2 0.70710678118654752440f

typedef __attribute__((ext_vector_type(8))) short short8;
typedef __attribute__((ext_vector_type(4))) float floatx4;
typedef __attribute__((ext_vector_type(4))) unsigned short ushort4v;
typedef unsigned short u16;
typedef unsigned int u32;

__device__ __forceinline__ float bf2f(u16 u){ u32 x = ((u32)u)<<16; return __builtin_bit_cast(float, x); }
__device__ __forceinline__ u16 f2bf(float f){ u32 u = __builtin_bit_cast(u32, f); u += 0x7FFFu + ((u>>16)&1u); return (u16)(u>>16); }
// ScaledSiLU: silu(x)/0.6
__device__ __forceinline__ float actf(float x){
  float e = __expf(-x);
  float s = __builtin_amdgcn_rcpf(1.0f + e);
  return x * s * (1.0f/0.6f);
}

// ---------------- weight prep: fp32 (K,N) -> bf16 (N,K) transposed ----------------
struct TEntry { const float* s; u16* d; int K; int N; };
struct TArgs { TEntry e[24]; };
__global__ __launch_bounds__(256) void prep_k(TArgs a){
  TEntry en = a.e[blockIdx.y];
  long total = (long)en.K * en.N;
  for (long i = (long)blockIdx.x*256 + threadIdx.x; i < total; i += (long)gridDim.x*256){
    long n = i / en.K, k = i - n*en.K;
    en.d[i] = f2bf(en.s[k*(long)en.N + n]);
  }
}

// ---------------- generic MFMA GEMM: Out(M,N) = EP(A(M,K) @ Wt(N,K)^T) ----------------
// AMODE: 0=A bf16, 1=A fp32, 2=concat gather [h_new[id_c]|h_new[id_a]|m_new]
// EP: 0=none 1=act 2=act*Had 3=(r1+act)*c 4=(r2+(r1+act)*c)*c ; OUTF/R1F/R2F: 1=f32, 0=bf16
struct GemmArgs {
  const void* A; const u16* Bt; void* Out;
  const u16* Had; const void* Res1; const void* Res2;
  const float* Hn; const u16* Mn; const int* idc; const int* ida;
  int M, N, K;
};

template<int BM,int BN,int WGM,int WGN,int AMODE,int EP,int OUTF,int R1F,int R2F>
__global__ __launch_bounds__(256)
void gemm_k(GemmArgs g){
  constexpr int LDK = 40;  // 32 + 8 pad -> 80B row stride, only 2-way LDS conflicts (free)
  __shared__ __align__(16) u16 As[BM*LDK];
  __shared__ __align__(16) u16 Bs[BN*LDK];
  constexpr int WM = BM/(WGM*16), WN = BN/(WGN*16);
  const int t = threadIdx.x;
  const long row0 = (long)blockIdx.x*BM;
  const int col0 = blockIdx.y*BN;
  const int wave = t>>6, lane = t&63;
  const int wm = wave/WGN, wn = wave%WGN;
  const int lrow = lane&15, q = lane>>4;
  floatx4 acc[WM][WN];
#pragma unroll
  for (int a=0;a<WM;a++)
#pragma unroll
    for (int b=0;b<WN;b++) acc[a][b] = (floatx4){0.f,0.f,0.f,0.f};

  for (int k0=0; k0<g.K; k0+=32){
    // ---- stage A tile (BM x 32 bf16) ----
#pragma unroll
    for (int c = t; c < BM*4; c += 256){
      const int r = c>>2, kc = (c&3)*8;
      const long gr = row0 + r; const int gk = k0 + kc;
      short8 v = {0,0,0,0,0,0,0,0};
      if (gr < g.M && gk < g.K){
        if constexpr (AMODE==0){
          v = *(const short8*)((const u16*)g.A + gr*(long)g.K + gk);
        } else if constexpr (AMODE==1){
          const float* ap = (const float*)g.A + gr*(long)g.K + gk;
          floatx4 a0 = *(const floatx4*)ap, a1 = *(const floatx4*)(ap+4);
#pragma unroll
          for (int j=0;j<4;j++){ v[j]=(short)f2bf(a0[j]); v[j+4]=(short)f2bf(a1[j]); }
        } else {
          if (gk < DAH){
            const float* hp = g.Hn + (long)g.idc[gr]*DAH + gk;
            floatx4 a0 = *(const floatx4*)hp, a1 = *(const floatx4*)(hp+4);
#pragma unroll
            for (int j=0;j<4;j++){ v[j]=(short)f2bf(a0[j]); v[j+4]=(short)f2bf(a1[j]); }
          } else if (gk < 2*DAH){
            const float* hp = g.Hn + (long)g.ida[gr]*DAH + (gk-DAH);
            floatx4 a0 = *(const floatx4*)hp, a1 = *(const floatx4*)(hp+4);
#pragma unroll
            for (int j=0;j<4;j++){ v[j]=(short)f2bf(a0[j]); v[j+4]=(short)f2bf(a1[j]); }
          } else {
            v = *(const short8*)(g.Mn + gr*(long)DE + (gk-2*DAH));
          }
        }
      }
      *(short8*)&As[r*LDK + kc] = v;
    }
    // ---- stage B tile (BN x 32 bf16) from pre-transposed Wt(N,K) ----
#pragma unroll
    for (int c = t; c < BN*4; c += 256){
      const int n = c>>2, kc = (c&3)*8;
      const int gn = col0 + n, gk = k0 + kc;
      short8 v = {0,0,0,0,0,0,0,0};
      if (gn < g.N && gk < g.K) v = *(const short8*)(g.Bt + (long)gn*g.K + gk);
      *(short8*)&Bs[n*LDK + kc] = v;
    }
    __syncthreads();
    short8 af[WM], bfr[WN];
#pragma unroll
    for (int mi=0;mi<WM;mi++) af[mi]  = *(const short8*)&As[(wm*WM*16 + mi*16 + lrow)*LDK + q*8];
#pragma unroll
    for (int ni=0;ni<WN;ni++) bfr[ni] = *(const short8*)&Bs[(wn*WN*16 + ni*16 + lrow)*LDK + q*8];
#pragma unroll
    for (int mi=0;mi<WM;mi++)
#pragma unroll
      for (int ni=0;ni<WN;ni++)
        acc[mi][ni] = __builtin_amdgcn_mfma_f32_16x16x32_bf16(af[mi], bfr[ni], acc[mi][ni], 0,0,0);
    __syncthreads();
  }
  // ---- epilogue: C/D layout col=lane&15, row=quad*4+reg ----
#pragma unroll
  for (int mi=0;mi<WM;mi++){
#pragma unroll
    for (int ni=0;ni<WN;ni++){
      const int gcol = col0 + wn*WN*16 + ni*16 + lrow;
      if (gcol < g.N){
#pragma unroll
        for (int r=0;r<4;r++){
          const long grow = row0 + wm*WM*16 + mi*16 + q*4 + r;
          if (grow < g.M){
            float v = acc[mi][ni][r];
            const long oi = grow*(long)g.N + gcol;
            if constexpr (EP==1) v = actf(v);
            if constexpr (EP==2) v = actf(v) * bf2f(g.Had[oi]);
            if constexpr (EP==3){
              float r1 = R1F ? ((const float*)g.Res1)[oi] : bf2f(((const u16*)g.Res1)[oi]);
              v = (r1 + actf(v)) * INV2;
            }
            if constexpr (EP==4){
              float r1 = R1F ? ((const float*)g.Res1)[oi] : bf2f(((const u16*)g.Res1)[oi]);
              float r2 = R2F ? ((const float*)g.Res2)[oi] : bf2f(((const u16*)g.Res2)[oi]);
              v = (r2 + (r1 + actf(v))*INV2) * INV2;
            }
            if constexpr (OUTF) ((float*)g.Out)[oi] = v;
            else ((u16*)g.Out)[oi] = f2bf(v);
          }
        }
      }
    }
  }
}

// ---------------- triplet: gather m2, contract cbf_sph then cbf_W1 -> rW_flat(NE,1024) bf16 ----------------
// rW_flat[e][i*16+j] = sum_s cbf_W1[e,j,s] * (sum_k cbf_sph[e,k,s] * x_ba2[id3e[e*10+k], i])
__global__ __launch_bounds__(256) void trip_k(const u16* __restrict__ xba2,
    const float* __restrict__ cbf_sph, const float* __restrict__ cbf_w1,
    const int* __restrict__ id3e, u16* __restrict__ rw){
  const int e = blockIdx.x*4 + (threadIdx.x>>6);
  if (e >= NE) return;
  const int lane = threadIdx.x & 63;   // lane = i (T dim)
  float m2[KM];
#pragma unroll
  for (int k=0;k<KM;k++){
    const int idx = id3e[e*KM + k];
    m2[k] = bf2f(xba2[(long)idx*DT + lane]);
  }
  const float* sph = cbf_sph + (long)e*KM*NS;
  float sk[NS];
#pragma unroll
  for (int s=0;s<NS;s++){
    float acc = 0.f;
#pragma unroll
    for (int k=0;k<KM;k++) acc += sph[k*NS+s]*m2[k];
    sk[s] = acc;
  }
  const float* w1 = cbf_w1 + (long)e*16*NS;
  short8 v0, v1;
#pragma unroll
  for (int j=0;j<16;j++){
    float acc = 0.f;
#pragma unroll
    for (int s=0;s<NS;s++) acc += w1[j*NS+s]*sk[s];
    if (j<8) v0[j] = (short)f2bf(acc); else v1[j-8] = (short)f2bf(acc);
  }
  u16* dst = rw + (long)e*1024 + lane*16;
  *(short8*)dst = v0;
  *(short8*)(dst+8) = v1;
}

// ---------------- combine: X = (skip + (x_ca + x_ac[swap])*c)*c, in-place into C ----------------
__global__ __launch_bounds__(256) void comb_k(const u16* __restrict__ S, u16* __restrict__ C,
    const u16* __restrict__ D, const int* __restrict__ swp){
  const long i = ((long)blockIdx.x*256 + threadIdx.x)*8;
  if (i >= (long)NE*DE) return;
  const long r = i >> 9; const int c = (int)(i & 511);
  const int sr = swp[r];
  short8 s8 = *(const short8*)(S+i);
  short8 c8 = *(const short8*)(C+i);
  short8 d8 = *(const short8*)(D + (long)sr*DE + c);
  short8 o;
#pragma unroll
  for (int j=0;j<8;j++)
    o[j] = (short)f2bf((bf2f((u16)s8[j]) + (bf2f((u16)c8[j]) + bf2f((u16)d8[j]))*INV2)*INV2);
  *(short8*)(C+i) = o;
}

// ---------------- CSR build for segment-sum gather ----------------
__global__ __launch_bounds__(256) void hist_k(const int* __restrict__ ida, int* __restrict__ cnt){
  const int e = blockIdx.x*256 + threadIdx.x;
  if (e < NE) atomicAdd(&cnt[ida[e]], 1);
}

// single-block exclusive scan over NA=5000 counts (256 thr x 20 chunk)
__global__ __launch_bounds__(256) void scan_k(const int* __restrict__ cnt,
    int* __restrict__ off, int* __restrict__ cur){
  __shared__ int s[256];
  const int t = threadIdx.x;
  const int base = t*20;
  int loc[20]; int sum = 0;
#pragma unroll
  for (int j=0;j<20;j++){
    int v = (base+j < NA) ? cnt[base+j] : 0;
    loc[j] = sum; sum += v;
  }
  s[t] = sum;
  __syncthreads();
  for (int d=1; d<256; d<<=1){
    int v = (t>=d) ? s[t-d] : 0;
    __syncthreads();
    s[t] += v;
    __syncthreads();
  }
  const int excl = (t==0) ? 0 : s[t-1];
#pragma unroll
  for (int j=0;j<20;j++){
    if (base+j < NA){ off[base+j] = excl + loc[j]; cur[base+j] = excl + loc[j]; }
  }
  if (t==255) off[NA] = s[255];
}

__global__ __launch_bounds__(256) void fill_k(const int* __restrict__ ida,
    int* __restrict__ cur, int* __restrict__ csr){
  const int e = blockIdx.x*256 + threadIdx.x;
  if (e >= NE) return;
  const int a = ida[e];
  const int pos = atomicAdd(&cur[a], 1);
  csr[pos] = e;
}

// ---------------- gather segment-sum, fused with rbf_h MLP ----------------
// x2[a, c] = sum_{e in edges(a)} m_new[e, c] * (rbf_h[e, :16] @ W_rbf_h[:16, c])
// one block per atom; thread t owns columns 2t, 2t+1. W columns preloaded to registers.
__global__ __launch_bounds__(256) void gath_k(const u16* __restrict__ mn,
    const float* __restrict__ rbfh, const u16* __restrict__ wt /* (N=512,K=16) bf16 */,
    const int* __restrict__ off, const int* __restrict__ csr, float* __restrict__ x2){
  const int a = blockIdx.x;
  const int t = threadIdx.x;
  float w0[16], w1[16];
  const u16* wp = wt + (t*2)*16;
#pragma unroll
  for (int k=0;k<16;k++){ w0[k] = bf2f(wp[k]); w1[k] = bf2f(wp[16+k]); }
  const int beg = off[a], end = off[a+1];
  float acc0 = 0.f, acc1 = 0.f;
  for (int i=beg; i<end; ++i){
    const int e = csr[i];
    const float* rp = rbfh + (long)e*DR;
    floatx4 r0 = *(const floatx4*)rp;
    floatx4 r1 = *(const floatx4*)(rp+4);
    floatx4 r2 = *(const floatx4*)(rp+8);
    floatx4 r3 = *(const floatx4*)(rp+12);
    const u32 mv = *(const u32*)(mn + ((long)e<<9) + t*2);
    float rb0 = 0.f, rb1 = 0.f;
#pragma unroll
    for (int j=0;j<4;j++){
      rb0 += r0[j]*w0[j]   + r1[j]*w0[4+j] + r2[j]*w0[8+j] + r3[j]*w0[12+j];
      rb1 += r0[j]*w1[j]   + r1[j]*w1[4+j] + r2[j]*w1[8+j] + r3[j]*w1[12+j];
    }
    acc0 += bf2f((u16)mv)       * rb0;
    acc1 += bf2f((u16)(mv>>16)) * rb1;
  }
  float* dst = x2 + ((long)a<<9) + t*2;
  dst[0] = acc0; dst[1] = acc1;
}

extern "C" void kernel_launch(void* const* d_in, const int* in_sizes, int n_in,
                              void* d_out, int out_size, void* d_ws, size_t ws_size,
                              hipStream_t stream){
  (void)in_sizes; (void)n_in; (void)out_size; (void)ws_size;
  const float* h    = (const float*)d_in[0];
  const float* m    = (const float*)d_in[1];
  const float* rbf3 = (const float*)d_in[2];
  const float* cbfW1= (const float*)d_in[3];
  const float* cbfS = (const float*)d_in[4];
  const float* rbfh = (const float*)d_in[5];
  const float* W_dense=(const float*)d_in[6];
  const float* W_ba  =(const float*)d_in[7];
  const float* W_rbf3=(const float*)d_in[8];
  const float* W_down=(const float*)d_in[9];
  const float* W_bil =(const float*)d_in[10];
  const float* W_upca=(const float*)d_in[11];
  const float* W_upac=(const float*)d_in[12];
  const float* W_rb  =(const float*)d_in[13];
  const float* W_ra  =(const float*)d_in[14];
  const float* W_rbfh=(const float*)d_in[15];
  const float* W_ad  =(const float*)d_in[16];
  const float* W_ar  =(const float*)d_in[17];
  const float* W_cat =(const float*)d_in[18];
  const float* W_rm  =(const float*)d_in[19];
  const int* id_swap =(const int*)d_in[21];
  const int* id3e    =(const int*)d_in[22];
  const int* id_c    =(const int*)d_in[24];
  const int* id_a    =(const int*)d_in[25];

  char* p = (char*)d_ws;
  auto alloc = [&](size_t b)->char*{ char* r=p; p += (b+255)&~(size_t)255; return r; };

  const size_t SLOT = (size_t)NE*DE*2;               // 102.4 MB bf16 slot
  u16* BIG = (u16*)alloc(4*SLOT);
  u16* B0 = BIG;                   // tmp_rbf3 -> rW(lo) -> x_ac -> mn_mid -> rm_y
  u16* B1 = BIG + SLOT/2;          // x_ba1 -> rW(hi) -> res y -> mc
  u16* B2 = BIG + 2*(SLOT/2);      // x_ca_skip -> m_new -> m_new_final
  u16* B3 = BIG + 3*(SLOT/2);      // x_ca -> X
  u16* rw = B0;                    // spans B0+B1 (100k x 1024 bf16)

  u16* wt_dense=(u16*)alloc(512*512*2);
  u16* wt_ba   =(u16*)alloc(512*512*2);
  u16* wt_rbf3 =(u16*)alloc(16*512*2);
  u16* wt_down =(u16*)alloc(512*64*2);
  u16* wt_bil  =(u16*)alloc(1024*64*2);
  u16* wt_upca =(u16*)alloc(64*512*2);
  u16* wt_upac =(u16*)alloc(64*512*2);
  u16* wt_rb0  =(u16*)alloc(512*512*2);
  u16* wt_rb1  =(u16*)alloc(512*512*2);
  u16* wt_ra[4]; for (int i=0;i<4;i++) wt_ra[i]=(u16*)alloc(512*512*2);
  u16* wt_rbfh =(u16*)alloc(16*512*2);
  u16* wt_ad   =(u16*)alloc(512*128*2);
  u16* wt_ar[6]; for (int i=0;i<6;i++) wt_ar[i]=(u16*)alloc(128*128*2);
  u16* wt_cat  =(u16*)alloc(768*512*2);
  u16* wt_rm0  =(u16*)alloc(512*512*2);
  u16* wt_rm1  =(u16*)alloc(512*512*2);
  u16* xba2 = (u16*)alloc((size_t)NE*DT*2);
  u16* xbil = (u16*)alloc((size_t)NE*DT*2);
  float* x2 = (float*)alloc((size_t)NA*DE*4);
  float* xa = (float*)alloc((size_t)NA*DAH*4);
  float* yb = (float*)alloc((size_t)NA*DAH*4);
  int* csr_cnt = (int*)alloc((size_t)NA*4);
  int* csr_off = (int*)alloc((size_t)(NA+1)*4);
  int* csr_cur = (int*)alloc((size_t)NA*4);
  int* csr_edg = (int*)alloc((size_t)NE*4);
  float* out_h = (float*)d_out;
  float* out_m = (float*)d_out + (size_t)NA*DAH;

  // ---- weight prep ----
  TArgs ta;
  int ti=0;
  auto te=[&](const float* s, u16* d, int K, int N){ ta.e[ti++] = {s,d,K,N}; };
  te(W_dense,wt_dense,512,512); te(W_ba,wt_ba,512,512); te(W_rbf3,wt_rbf3,16,512);
  te(W_down,wt_down,512,64);   te(W_bil,wt_bil,1024,64);
  te(W_upca,wt_upca,64,512);   te(W_upac,wt_upac,64,512);
  te(W_rb,wt_rb0,512,512);     te(W_rb+262144,wt_rb1,512,512);
  for (int i=0;i<4;i++) te(W_ra+(size_t)i*262144, wt_ra[i],512,512);
  te(W_rbfh,wt_rbfh,16,512);   te(W_ad,wt_ad,512,128);
  for (int i=0;i<6;i++) te(W_ar+(size_t)i*16384, wt_ar[i],128,128);
  te(W_cat,wt_cat,768,512);    te(W_rm,wt_rm0,512,512); te(W_rm+262144,wt_rm1,512,512);
  prep_k<<<dim3(128,24),256,0,stream>>>(ta);

  // ---- CSR build for the atom segment-sum (id_a is a launch input) ----
  hipMemsetAsync(csr_cnt, 0, (size_t)NA*4, stream);
  hist_k<<<(NE+255)/256,256,0,stream>>>(id_a, csr_cnt);
  scan_k<<<1,256,0,stream>>>(csr_cnt, csr_off, csr_cur);
  fill_k<<<(NE+255)/256,256,0,stream>>>(id_a, csr_cur, csr_edg);

  const dim3 GE128(782,4);   // M=NE, N=512, 128x128
  const dim3 GE64 (782,1);   // M=NE, N=64,  128x64
  const dim3 GAT  (40,2);    // M=NA, N=128, 128x64

  GemmArgs ga;
  // G1: tmp_rbf3 = rbf3 @ W_rbf3 -> B0
  ga = {}; ga.A=rbf3; ga.Bt=wt_rbf3; ga.Out=B0; ga.M=NE; ga.N=DE; ga.K=DR;
  gemm_k<128,128,2,2,1,0,0,0,0><<<GE128,256,0,stream>>>(ga);
  // G3: x_ca_skip = act(m @ W_dense) -> B2
  ga = {}; ga.A=m; ga.Bt=wt_dense; ga.Out=B2; ga.M=NE; ga.N=DE; ga.K=DE;
  gemm_k<128,128,2,2,1,1,0,0,0><<<GE128,256,0,stream>>>(ga);
  // G2: x_ba1 = act(m @ W_ba) * tmp_rbf3 -> B1
  ga = {}; ga.A=m; ga.Bt=wt_ba; ga.Out=B1; ga.Had=B0; ga.M=NE; ga.N=DE; ga.K=DE;
  gemm_k<128,128,2,2,1,2,0,0,0><<<GE128,256,0,stream>>>(ga);
  // G4: x_ba2 = act(x_ba1 @ W_down) -> xba2
  ga = {}; ga.A=B1; ga.Bt=wt_down; ga.Out=xba2; ga.M=NE; ga.N=DT; ga.K=DE;
  gemm_k<128,64,4,1,0,1,0,0,0><<<GE64,256,0,stream>>>(ga);
  // triplet contraction -> rW (B0+B1)
  trip_k<<<NE/4,256,0,stream>>>(xba2, cbfS, cbfW1, id3e, rw);
  // G_bil: x_bil = rW @ W_bil_flat -> xbil
  ga = {}; ga.A=rw; ga.Bt=wt_bil; ga.Out=xbil; ga.M=NE; ga.N=DT; ga.K=1024;
  gemm_k<128,64,4,1,0,0,0,0,0><<<GE64,256,0,stream>>>(ga);
  // G6: x_ca = act(x_bil @ W_up_ca) -> B3
  ga = {}; ga.A=xbil; ga.Bt=wt_upca; ga.Out=B3; ga.M=NE; ga.N=DE; ga.K=DT;
  gemm_k<128,128,2,2,0,1,0,0,0><<<GE128,256,0,stream>>>(ga);
  // G7: x_ac = act(x_bil @ W_up_ac) -> B0
  ga = {}; ga.A=xbil; ga.Bt=wt_upac; ga.Out=B0; ga.M=NE; ga.N=DE; ga.K=DT;
  gemm_k<128,128,2,2,0,1,0,0,0><<<GE128,256,0,stream>>>(ga);
  // combine -> X in B3 (in-place)
  comb_k<<<NE*DE/8/256,256,0,stream>>>(B2, B3, B0, id_swap);
  // res_before: y = act(X @ Wrb0) -> B1
  ga = {}; ga.A=B3; ga.Bt=wt_rb0; ga.Out=B1; ga.M=NE; ga.N=DE; ga.K=DE;
  gemm_k<128,128,2,2,0,1,0,0,0><<<GE128,256,0,stream>>>(ga);
  // m_new = (m + (X + act(y @ Wrb1))*c)*c -> B2
  ga = {}; ga.A=B1; ga.Bt=wt_rb1; ga.Out=B2; ga.Res1=B3; ga.Res2=m; ga.M=NE; ga.N=DE; ga.K=DE;
  gemm_k<128,128,2,2,0,4,0,0,1><<<GE128,256,0,stream>>>(ga);
  // res_after[0]
  ga = {}; ga.A=B2; ga.Bt=wt_ra[0]; ga.Out=B1; ga.M=NE; ga.N=DE; ga.K=DE;
  gemm_k<128,128,2,2,0,1,0,0,0><<<GE128,256,0,stream>>>(ga);
  ga = {}; ga.A=B1; ga.Bt=wt_ra[1]; ga.Out=B0; ga.Res1=B2; ga.M=NE; ga.N=DE; ga.K=DE;
  gemm_k<128,128,2,2,0,3,0,0,0><<<GE128,256,0,stream>>>(ga);
  // res_after[1] -> final m_new in B2
  ga = {}; ga.A=B0; ga.Bt=wt_ra[2]; ga.Out=B1; ga.M=NE; ga.N=DE; ga.K=DE;
  gemm_k<128,128,2,2,0,1,0,0,0><<<GE128,256,0,stream>>>(ga);
  ga = {}; ga.A=B1; ga.Bt=wt_ra[3]; ga.Out=B2; ga.Res1=B0; ga.M=NE; ga.N=DE; ga.K=DE;
  gemm_k<128,128,2,2,0,3,0,0,0><<<GE128,256,0,stream>>>(ga);
  // segment sum (gather, CSR) fused with rbf_h MLP -> x2 (f32)
  gath_k<<<NA,256,0,stream>>>(B2, rbfh, wt_rbfh, csr_off, csr_edg, x2);
  // xa = act(x2 @ W_atom_dense) -> xa (f32)
  ga = {}; ga.A=x2; ga.Bt=wt_ad; ga.Out=xa; ga.M=NA; ga.N=DAH; ga.K=DE;
  gemm_k<128,64,4,1,1,1,1,0,0><<<GAT,256,0,stream>>>(ga);
  // atom residuals 0,1
  for (int i=0;i<2;i++){
    ga = {}; ga.A=xa; ga.Bt=wt_ar[2*i]; ga.Out=yb; ga.M=NA; ga.N=DAH; ga.K=DAH;
    gemm_k<128,64,4,1,1,1,1,0,0><<<GAT,256,0,stream>>>(ga);
    ga = {}; ga.A=yb; ga.Bt=wt_ar[2*i+1]; ga.Out=xa; ga.Res1=xa; ga.M=NA; ga.N=DAH; ga.K=DAH;
    gemm_k<128,64,4,1,1,3,1,1,0><<<GAT,256,0,stream>>>(ga);
  }
  // atom residual 2 fused with h_new = (h + xa')*c -> d_out
  ga = {}; ga.A=xa; ga.Bt=wt_ar[4]; ga.Out=yb; ga.M=NA; ga.N=DAH; ga.K=DAH;
  gemm_k<128,64,4,1,1,1,1,0,0><<<GAT,256,0,stream>>>(ga);
  ga = {}; ga.A=yb; ga.Bt=wt_ar[5]; ga.Out=out_h; ga.Res1=xa; ga.Res2=h; ga.M=NA; ga.N=DAH; ga.K=DAH;
  gemm_k<128,64,4,1,1,4,1,1,1><<<GAT,256,0,stream>>>(ga);
  // concat GEMM: mc = act([h_new[id_c]|h_new[id_a]|m_new] @ W_concat) -> B1
  ga = {}; ga.Bt=wt_cat; ga.Out=B1; ga.Hn=out_h; ga.Mn=B2; ga.idc=id_c; ga.ida=id_a;
  ga.M=NE; ga.N=DE; ga.K=2*DAH+DE;
  gemm_k<128,128,2,2,2,1,0,0,0><<<GE128,256,0,stream>>>(ga);
  // res_m: y = act(mc @ Wrm0) -> B0
  ga = {}; ga.A=B1; ga.Bt=wt_rm0; ga.Out=B0; ga.M=NE; ga.N=DE; ga.K=DE;
  gemm_k<128,128,2,2,0,1,0,0,0><<<GE128,256,0,stream>>>(ga);
  // m_out = (m_new + (mc + act(y @ Wrm1))*c)*c -> d_out
  ga = {}; ga.A=B0; ga.Bt=wt_rm1; ga.Out=out_m; ga.Res1=B1; ga.Res2=B2; ga.M=NE; ga.N=DE; ga.K=DE;
  gemm_k<128,128,2,2,0,4,1,0,0><<<GE128,256,0,stream>>>(ga);
}

// Round 4
// 2752.962 us; speedup vs baseline: 1.4798x; 1.2518x over previous
//
#include <hip/hip_runtime.h>
#include <cstdint>

#define NE 100000   // edges
#define NA 5000     // atoms
#define DE 512      // edge feat
#define DAH 128     // atom feat
#define DT 64       // T
#define NS 7
#define KM 10
#define DR 16
#define INV2 0.70710678118654752440f

typedef __attribute__((ext_vector_type(8))) short short8;
typedef __attribute__((ext_vector_type(4))) float floatx4;
typedef __attribute__((ext_vector_type(4))) unsigned short ushort4v;
typedef unsigned short u16;
typedef unsigned int u32;

__device__ __forceinline__ float bf2f(u16 u){ u32 x = ((u32)u)<<16; return __builtin_bit_cast(float, x); }
__device__ __forceinline__ u16 f2bf(float f){ u32 u = __builtin_bit_cast(u32, f); u += 0x7FFFu + ((u>>16)&1u); return (u16)(u>>16); }
// ScaledSiLU: silu(x)/0.6
__device__ __forceinline__ float actf(float x){
  float e = __expf(-x);
  float s = __builtin_amdgcn_rcpf(1.0f + e);
  return x * s * (1.0f/0.6f);
}

// async 16B global->LDS; lds ptr must be wave-uniform (lane l lands at lds + l*16B)
__device__ __forceinline__ void gl16(const u16* g, u16* l){
  __builtin_amdgcn_global_load_lds(
      (const __attribute__((address_space(1))) u32*)g,
      (__attribute__((address_space(3))) u32*)l, 16, 0, 0);
}

// ---------------- weight prep: fp32 (K,N) -> bf16 (N,K) transposed ----------------
struct TEntry { const float* s; u16* d; int K; int N; };
struct TArgs { TEntry e[24]; };
__global__ __launch_bounds__(256) void prep_k(TArgs a){
  TEntry en = a.e[blockIdx.y];
  long total = (long)en.K * en.N;
  for (long i = (long)blockIdx.x*256 + threadIdx.x; i < total; i += (long)gridDim.x*256){
    long n = i / en.K, k = i - n*en.K;
    en.d[i] = f2bf(en.s[k*(long)en.N + n]);
  }
}

// ---------------- m fp32 -> bf16 ----------------
__global__ __launch_bounds__(256) void mb_k(const float* __restrict__ src, u16* __restrict__ dst){
  const long i = ((long)blockIdx.x*256 + threadIdx.x)*8;
  if (i >= (long)NE*DE) return;
  floatx4 a0 = *(const floatx4*)(src+i), a1 = *(const floatx4*)(src+i+4);
  short8 v;
#pragma unroll
  for (int j=0;j<4;j++){ v[j]=(short)f2bf(a0[j]); v[j+4]=(short)f2bf(a1[j]); }
  *(short8*)(dst+i) = v;
}

// ---------------- generic MFMA GEMM: Out(M,N) = EP(A(M,K) @ Wt(N,K)^T) ----------------
// AMODE: 0=A bf16 (async gload_lds), 1=A fp32 (reg-stage), 2=concat gather (reg-stage)
// EP: 0=none 1=act 2=act*Had 3=(r1+act)*c 4=(r2+(r1+act)*c)*c ; OUTF/R1F/R2F: 1=f32, 0=bf16
// LDS is linear [row][32]; bank-conflict-free via XOR chunk swizzle s(r)=(r+(r>>2))&3
// applied to the GLOBAL source chunk (gload) / LDS write chunk (reg-stage) and to reads.
struct GemmArgs {
  const void* A; const u16* Bt; void* Out;
  const u16* Had; const void* Res1; const void* Res2;
  const float* Hn; const u16* Mn; const int* idc; const int* ida;
  int M, N, K;
};

template<int BM,int BN,int WGM,int WGN,int AMODE,int EP,int OUTF,int R1F,int R2F>
__global__ __launch_bounds__(256)
void gemm_k(GemmArgs g){
  __shared__ __align__(16) u16 As[BM*32];
  __shared__ __align__(16) u16 Bs[BN*32];
  constexpr int WM = BM/(WGM*16), WN = BN/(WGN*16);
  const int t = threadIdx.x;
  const long row0 = (long)blockIdx.x*BM;
  const int col0 = blockIdx.y*BN;
  const int wave = t>>6, lane = t&63;
  const int wm = wave/WGN, wn = wave%WGN;
  const int lrow = lane&15, q = lane>>4;
  const int sr4 = lane>>2, ch = lane&3;   // staging: row-in-slot, chunk
  floatx4 acc[WM][WN];
#pragma unroll
  for (int a=0;a<WM;a++)
#pragma unroll
    for (int b=0;b<WN;b++) acc[a][b] = (floatx4){0.f,0.f,0.f,0.f};

  for (int k0=0; k0<g.K; k0+=32){
    if (k0) __syncthreads();   // prev tile reads complete before overwrite
    // ---- B tile: async gload (Bt bf16 (N,K)); swizzled source chunk ----
#pragma unroll
    for (int i=0;i<BN/64;i++){
      const int slot = wave*(BN/64) + i;
      const int rb = slot*16 + sr4;
      const int sw = ch ^ ((rb + (rb>>2)) & 3);
      gl16(g.Bt + (long)(col0+rb)*g.K + k0 + (sw<<3), &Bs[slot*512]);
    }
    // ---- A tile ----
    if constexpr (AMODE==0){
#pragma unroll
      for (int i=0;i<BM/64;i++){
        const int slot = wave*(BM/64) + i;
        const int ra = slot*16 + sr4;
        const int sw = ch ^ ((ra + (ra>>2)) & 3);
        gl16((const u16*)g.A + (row0+ra)*(long)g.K + k0 + (sw<<3), &As[slot*512]);
      }
    } else {
#pragma unroll
      for (int c = t; c < BM*4; c += 256){
        const int r = c>>2, kch = c&3, kc = kch*8;
        const long gr = row0 + r; const int gk = k0 + kc;
        short8 v = {0,0,0,0,0,0,0,0};
        if (gr < g.M && gk < g.K){
          if constexpr (AMODE==1){
            const float* ap = (const float*)g.A + gr*(long)g.K + gk;
            floatx4 a0 = *(const floatx4*)ap, a1 = *(const floatx4*)(ap+4);
#pragma unroll
            for (int j=0;j<4;j++){ v[j]=(short)f2bf(a0[j]); v[j+4]=(short)f2bf(a1[j]); }
          } else {
            if (gk < DAH){
              const float* hp = g.Hn + (long)g.idc[gr]*DAH + gk;
              floatx4 a0 = *(const floatx4*)hp, a1 = *(const floatx4*)(hp+4);
#pragma unroll
              for (int j=0;j<4;j++){ v[j]=(short)f2bf(a0[j]); v[j+4]=(short)f2bf(a1[j]); }
            } else if (gk < 2*DAH){
              const float* hp = g.Hn + (long)g.ida[gr]*DAH + (gk-DAH);
              floatx4 a0 = *(const floatx4*)hp, a1 = *(const floatx4*)(hp+4);
#pragma unroll
              for (int j=0;j<4;j++){ v[j]=(short)f2bf(a0[j]); v[j+4]=(short)f2bf(a1[j]); }
            } else {
              v = *(const short8*)(g.Mn + gr*(long)DE + (gk-2*DAH));
            }
          }
        }
        const int dch = kch ^ ((r + (r>>2)) & 3);
        *(short8*)&As[r*32 + dch*8] = v;
      }
    }
    __syncthreads();   // drains vmcnt(0): gload tiles landed
    short8 af[WM], bfr[WN];
#pragma unroll
    for (int mi=0;mi<WM;mi++){
      const int R = wm*WM*16 + mi*16 + lrow;
      af[mi] = *(const short8*)&As[R*32 + ((q ^ ((R + (R>>2))&3))<<3)];
    }
#pragma unroll
    for (int ni=0;ni<WN;ni++){
      const int R = wn*WN*16 + ni*16 + lrow;
      bfr[ni] = *(const short8*)&Bs[R*32 + ((q ^ ((R + (R>>2))&3))<<3)];
    }
#pragma unroll
    for (int mi=0;mi<WM;mi++)
#pragma unroll
      for (int ni=0;ni<WN;ni++)
        acc[mi][ni] = __builtin_amdgcn_mfma_f32_16x16x32_bf16(af[mi], bfr[ni], acc[mi][ni], 0,0,0);
  }
  // ---- epilogue: C/D layout col=lane&15, row=quad*4+reg ----
#pragma unroll
  for (int mi=0;mi<WM;mi++){
#pragma unroll
    for (int ni=0;ni<WN;ni++){
      const int gcol = col0 + wn*WN*16 + ni*16 + lrow;
      if (gcol < g.N){
#pragma unroll
        for (int r=0;r<4;r++){
          const long grow = row0 + wm*WM*16 + mi*16 + q*4 + r;
          if (grow < g.M){
            float v = acc[mi][ni][r];
            const long oi = grow*(long)g.N + gcol;
            if constexpr (EP==1) v = actf(v);
            if constexpr (EP==2) v = actf(v) * bf2f(g.Had[oi]);
            if constexpr (EP==3){
              float r1 = R1F ? ((const float*)g.Res1)[oi] : bf2f(((const u16*)g.Res1)[oi]);
              v = (r1 + actf(v)) * INV2;
            }
            if constexpr (EP==4){
              float r1 = R1F ? ((const float*)g.Res1)[oi] : bf2f(((const u16*)g.Res1)[oi]);
              float r2 = R2F ? ((const float*)g.Res2)[oi] : bf2f(((const u16*)g.Res2)[oi]);
              v = (r2 + (r1 + actf(v))*INV2) * INV2;
            }
            if constexpr (OUTF) ((float*)g.Out)[oi] = v;
            else ((u16*)g.Out)[oi] = f2bf(v);
          }
        }
      }
    }
  }
}

// ---------------- triplet: gather m2, contract cbf_sph then cbf_W1 -> rW_flat(NE,1024) bf16 ----------------
__global__ __launch_bounds__(256) void trip_k(const u16* __restrict__ xba2,
    const float* __restrict__ cbf_sph, const float* __restrict__ cbf_w1,
    const int* __restrict__ id3e, u16* __restrict__ rw){
  const int e = blockIdx.x*4 + (threadIdx.x>>6);
  if (e >= NE) return;
  const int lane = threadIdx.x & 63;   // lane = i (T dim)
  float m2[KM];
#pragma unroll
  for (int k=0;k<KM;k++){
    const int idx = id3e[e*KM + k];
    m2[k] = bf2f(xba2[(long)idx*DT + lane]);
  }
  const float* sph = cbf_sph + (long)e*KM*NS;
  float sk[NS];
#pragma unroll
  for (int s=0;s<NS;s++){
    float acc = 0.f;
#pragma unroll
    for (int k=0;k<KM;k++) acc += sph[k*NS+s]*m2[k];
    sk[s] = acc;
  }
  const float* w1 = cbf_w1 + (long)e*16*NS;
  short8 v0, v1;
#pragma unroll
  for (int j=0;j<16;j++){
    float acc = 0.f;
#pragma unroll
    for (int s=0;s<NS;s++) acc += w1[j*NS+s]*sk[s];
    if (j<8) v0[j] = (short)f2bf(acc); else v1[j-8] = (short)f2bf(acc);
  }
  u16* dst = rw + (long)e*1024 + lane*16;
  *(short8*)dst = v0;
  *(short8*)(dst+8) = v1;
}

// ---------------- combine: X = (skip + (x_ca + x_ac[swap])*c)*c, in-place into C ----------------
__global__ __launch_bounds__(256) void comb_k(const u16* __restrict__ S, u16* __restrict__ C,
    const u16* __restrict__ D, const int* __restrict__ swp){
  const long i = ((long)blockIdx.x*256 + threadIdx.x)*8;
  if (i >= (long)NE*DE) return;
  const long r = i >> 9; const int c = (int)(i & 511);
  const int sr = swp[r];
  short8 s8 = *(const short8*)(S+i);
  short8 c8 = *(const short8*)(C+i);
  short8 d8 = *(const short8*)(D + (long)sr*DE + c);
  short8 o;
#pragma unroll
  for (int j=0;j<8;j++)
    o[j] = (short)f2bf((bf2f((u16)s8[j]) + (bf2f((u16)c8[j]) + bf2f((u16)d8[j]))*INV2)*INV2);
  *(short8*)(C+i) = o;
}

// ---------------- CSR build for segment-sum gather ----------------
__global__ __launch_bounds__(256) void hist_k(const int* __restrict__ ida, int* __restrict__ cnt){
  const int e = blockIdx.x*256 + threadIdx.x;
  if (e < NE) atomicAdd(&cnt[ida[e]], 1);
}

__global__ __launch_bounds__(256) void scan_k(const int* __restrict__ cnt,
    int* __restrict__ off, int* __restrict__ cur){
  __shared__ int s[256];
  const int t = threadIdx.x;
  const int base = t*20;
  int loc[20]; int sum = 0;
#pragma unroll
  for (int j=0;j<20;j++){
    int v = (base+j < NA) ? cnt[base+j] : 0;
    loc[j] = sum; sum += v;
  }
  s[t] = sum;
  __syncthreads();
  for (int d=1; d<256; d<<=1){
    int v = (t>=d) ? s[t-d] : 0;
    __syncthreads();
    s[t] += v;
    __syncthreads();
  }
  const int excl = (t==0) ? 0 : s[t-1];
#pragma unroll
  for (int j=0;j<20;j++){
    if (base+j < NA){ off[base+j] = excl + loc[j]; cur[base+j] = excl + loc[j]; }
  }
  if (t==255) off[NA] = s[255];
}

__global__ __launch_bounds__(256) void fill_k(const int* __restrict__ ida,
    int* __restrict__ cur, int* __restrict__ csr){
  const int e = blockIdx.x*256 + threadIdx.x;
  if (e >= NE) return;
  const int a = ida[e];
  const int pos = atomicAdd(&cur[a], 1);
  csr[pos] = e;
}

// ---------------- gather segment-sum, fused with rbf_h MLP ----------------
__global__ __launch_bounds__(256) void gath_k(const u16* __restrict__ mn,
    const float* __restrict__ rbfh, const u16* __restrict__ wt /* (N=512,K=16) bf16 */,
    const int* __restrict__ off, const int* __restrict__ csr, float* __restrict__ x2){
  const int a = blockIdx.x;
  const int t = threadIdx.x;
  float w0[16], w1[16];
  const u16* wp = wt + (t*2)*16;
#pragma unroll
  for (int k=0;k<16;k++){ w0[k] = bf2f(wp[k]); w1[k] = bf2f(wp[16+k]); }
  const int beg = off[a], end = off[a+1];
  float acc0 = 0.f, acc1 = 0.f;
  for (int i=beg; i<end; ++i){
    const int e = csr[i];
    const float* rp = rbfh + (long)e*DR;
    floatx4 r0 = *(const floatx4*)rp;
    floatx4 r1 = *(const floatx4*)(rp+4);
    floatx4 r2 = *(const floatx4*)(rp+8);
    floatx4 r3 = *(const floatx4*)(rp+12);
    const u32 mv = *(const u32*)(mn + ((long)e<<9) + t*2);
    float rb0 = 0.f, rb1 = 0.f;
#pragma unroll
    for (int j=0;j<4;j++){
      rb0 += r0[j]*w0[j]   + r1[j]*w0[4+j] + r2[j]*w0[8+j] + r3[j]*w0[12+j];
      rb1 += r0[j]*w1[j]   + r1[j]*w1[4+j] + r2[j]*w1[8+j] + r3[j]*w1[12+j];
    }
    acc0 += bf2f((u16)mv)       * rb0;
    acc1 += bf2f((u16)(mv>>16)) * rb1;
  }
  float* dst = x2 + ((long)a<<9) + t*2;
  dst[0] = acc0; dst[1] = acc1;
}

extern "C" void kernel_launch(void* const* d_in, const int* in_sizes, int n_in,
                              void* d_out, int out_size, void* d_ws, size_t ws_size,
                              hipStream_t stream){
  (void)in_sizes; (void)n_in; (void)out_size;
  const float* h    = (const float*)d_in[0];
  const float* m    = (const float*)d_in[1];
  const float* rbf3 = (const float*)d_in[2];
  const float* cbfW1= (const float*)d_in[3];
  const float* cbfS = (const float*)d_in[4];
  const float* rbfh = (const float*)d_in[5];
  const float* W_dense=(const float*)d_in[6];
  const float* W_ba  =(const float*)d_in[7];
  const float* W_rbf3=(const float*)d_in[8];
  const float* W_down=(const float*)d_in[9];
  const float* W_bil =(const float*)d_in[10];
  const float* W_upca=(const float*)d_in[11];
  const float* W_upac=(const float*)d_in[12];
  const float* W_rb  =(const float*)d_in[13];
  const float* W_ra  =(const float*)d_in[14];
  const float* W_rbfh=(const float*)d_in[15];
  const float* W_ad  =(const float*)d_in[16];
  const float* W_ar  =(const float*)d_in[17];
  const float* W_cat =(const float*)d_in[18];
  const float* W_rm  =(const float*)d_in[19];
  const int* id_swap =(const int*)d_in[21];
  const int* id3e    =(const int*)d_in[22];
  const int* id_c    =(const int*)d_in[24];
  const int* id_a    =(const int*)d_in[25];

  char* p = (char*)d_ws;
  auto alloc = [&](size_t b)->char*{ char* r=p; p += (b+255)&~(size_t)255; return r; };

  const size_t SLOT = (size_t)NE*DE*2;               // 102.4 MB bf16 slot
  u16* BIG = (u16*)alloc(4*SLOT);
  u16* B0 = BIG;                   // tmp_rbf3 -> rW(lo) -> x_ac -> mn_mid -> rm_y
  u16* B1 = BIG + SLOT/2;          // x_ba1 -> rW(hi) -> res y -> mc
  u16* B2 = BIG + 2*(SLOT/2);      // x_ca_skip -> m_new -> m_new_final
  u16* B3 = BIG + 3*(SLOT/2);      // x_ca -> X
  u16* rw = B0;                    // spans B0+B1 (100k x 1024 bf16)

  u16* wt_dense=(u16*)alloc(512*512*2);
  u16* wt_ba   =(u16*)alloc(512*512*2);
  u16* wt_rbf3 =(u16*)alloc(16*512*2);
  u16* wt_down =(u16*)alloc(512*64*2);
  u16* wt_bil  =(u16*)alloc(1024*64*2);
  u16* wt_upca =(u16*)alloc(64*512*2);
  u16* wt_upac =(u16*)alloc(64*512*2);
  u16* wt_rb0  =(u16*)alloc(512*512*2);
  u16* wt_rb1  =(u16*)alloc(512*512*2);
  u16* wt_ra[4]; for (int i=0;i<4;i++) wt_ra[i]=(u16*)alloc(512*512*2);
  u16* wt_rbfh =(u16*)alloc(16*512*2);
  u16* wt_ad   =(u16*)alloc(512*128*2);
  u16* wt_ar[6]; for (int i=0;i<6;i++) wt_ar[i]=(u16*)alloc(128*128*2);
  u16* wt_cat  =(u16*)alloc(768*512*2);
  u16* wt_rm0  =(u16*)alloc(512*512*2);
  u16* wt_rm1  =(u16*)alloc(512*512*2);
  u16* xba2 = (u16*)alloc((size_t)NE*DT*2);
  u16* xbil = (u16*)alloc((size_t)NE*DT*2);
  float* x2 = (float*)alloc((size_t)NA*DE*4);
  float* xa = (float*)alloc((size_t)NA*DAH*4);
  float* yb = (float*)alloc((size_t)NA*DAH*4);
  int* csr_cnt = (int*)alloc((size_t)NA*4);
  int* csr_off = (int*)alloc((size_t)(NA+1)*4);
  int* csr_cur = (int*)alloc((size_t)NA*4);
  int* csr_edg = (int*)alloc((size_t)NE*4);
  float* out_h = (float*)d_out;
  float* out_m = (float*)d_out + (size_t)NA*DAH;

  // optional bf16 copy of m (enables async-staged A path for the big GEMMs)
  size_t used = (size_t)(p - (char*)d_ws);
  const bool use_mbf = ws_size > used + SLOT + (1u<<20);
  u16* mbf = nullptr;
  if (use_mbf) mbf = (u16*)alloc(SLOT + (1u<<17));   // +128KB overrun pad for gload tail rows

  // ---- weight prep ----
  TArgs ta;
  int ti=0;
  auto te=[&](const float* s, u16* d, int K, int N){ ta.e[ti++] = {s,d,K,N}; };
  te(W_dense,wt_dense,512,512); te(W_ba,wt_ba,512,512); te(W_rbf3,wt_rbf3,16,512);
  te(W_down,wt_down,512,64);   te(W_bil,wt_bil,1024,64);
  te(W_upca,wt_upca,64,512);   te(W_upac,wt_upac,64,512);
  te(W_rb,wt_rb0,512,512);     te(W_rb+262144,wt_rb1,512,512);
  for (int i=0;i<4;i++) te(W_ra+(size_t)i*262144, wt_ra[i],512,512);
  te(W_rbfh,wt_rbfh,16,512);   te(W_ad,wt_ad,512,128);
  for (int i=0;i<6;i++) te(W_ar+(size_t)i*16384, wt_ar[i],128,128);
  te(W_cat,wt_cat,768,512);    te(W_rm,wt_rm0,512,512); te(W_rm+262144,wt_rm1,512,512);
  prep_k<<<dim3(128,24),256,0,stream>>>(ta);

  if (use_mbf) mb_k<<<NE*DE/8/256,256,0,stream>>>(m, mbf);

  // ---- CSR build for the atom segment-sum ----
  hipMemsetAsync(csr_cnt, 0, (size_t)NA*4, stream);
  hist_k<<<(NE+255)/256,256,0,stream>>>(id_a, csr_cnt);
  scan_k<<<1,256,0,stream>>>(csr_cnt, csr_off, csr_cur);
  fill_k<<<(NE+255)/256,256,0,stream>>>(id_a, csr_cur, csr_edg);

  const dim3 GE128(782,4);   // M=NE, N=512, 128x128
  const dim3 GE64 (782,1);   // M=NE, N=64,  128x64
  const dim3 GAT  (40,2);    // M=NA, N=128, 128x64

  GemmArgs ga;
  // G1: tmp_rbf3 = rbf3 @ W_rbf3 -> B0   (K=16, f32 A)
  ga = {}; ga.A=rbf3; ga.Bt=wt_rbf3; ga.Out=B0; ga.M=NE; ga.N=DE; ga.K=DR;
  gemm_k<128,128,2,2,1,0,0,0,0><<<GE128,256,0,stream>>>(ga);
  // G3: x_ca_skip = act(m @ W_dense) -> B2
  if (use_mbf){
    ga = {}; ga.A=mbf; ga.Bt=wt_dense; ga.Out=B2; ga.M=NE; ga.N=DE; ga.K=DE;
    gemm_k<128,128,2,2,0,1,0,0,0><<<GE128,256,0,stream>>>(ga);
  } else {
    ga = {}; ga.A=m; ga.Bt=wt_dense; ga.Out=B2; ga.M=NE; ga.N=DE; ga.K=DE;
    gemm_k<128,128,2,2,1,1,0,0,0><<<GE128,256,0,stream>>>(ga);
  }
  // G2: x_ba1 = act(m @ W_ba) * tmp_rbf3 -> B1
  if (use_mbf){
    ga = {}; ga.A=mbf; ga.Bt=wt_ba; ga.Out=B1; ga.Had=B0; ga.M=NE; ga.N=DE; ga.K=DE;
    gemm_k<128,128,2,2,0,2,0,0,0><<<GE128,256,0,stream>>>(ga);
  } else {
    ga = {}; ga.A=m; ga.Bt=wt_ba; ga.Out=B1; ga.Had=B0; ga.M=NE; ga.N=DE; ga.K=DE;
    gemm_k<128,128,2,2,1,2,0,0,0><<<GE128,256,0,stream>>>(ga);
  }
  // G4: x_ba2 = act(x_ba1 @ W_down) -> xba2
  ga = {}; ga.A=B1; ga.Bt=wt_down; ga.Out=xba2; ga.M=NE; ga.N=DT; ga.K=DE;
  gemm_k<128,64,4,1,0,1,0,0,0><<<GE64,256,0,stream>>>(ga);
  // triplet contraction -> rW (B0+B1)
  trip_k<<<NE/4,256,0,stream>>>(xba2, cbfS, cbfW1, id3e, rw);
  // G_bil: x_bil = rW @ W_bil_flat -> xbil
  ga = {}; ga.A=rw; ga.Bt=wt_bil; ga.Out=xbil; ga.M=NE; ga.N=DT; ga.K=1024;
  gemm_k<128,64,4,1,0,0,0,0,0><<<GE64,256,0,stream>>>(ga);
  // G6: x_ca = act(x_bil @ W_up_ca) -> B3
  ga = {}; ga.A=xbil; ga.Bt=wt_upca; ga.Out=B3; ga.M=NE; ga.N=DE; ga.K=DT;
  gemm_k<128,128,2,2,0,1,0,0,0><<<GE128,256,0,stream>>>(ga);
  // G7: x_ac = act(x_bil @ W_up_ac) -> B0
  ga = {}; ga.A=xbil; ga.Bt=wt_upac; ga.Out=B0; ga.M=NE; ga.N=DE; ga.K=DT;
  gemm_k<128,128,2,2,0,1,0,0,0><<<GE128,256,0,stream>>>(ga);
  // combine -> X in B3 (in-place)
  comb_k<<<NE*DE/8/256,256,0,stream>>>(B2, B3, B0, id_swap);
  // res_before: y = act(X @ Wrb0) -> B1
  ga = {}; ga.A=B3; ga.Bt=wt_rb0; ga.Out=B1; ga.M=NE; ga.N=DE; ga.K=DE;
  gemm_k<128,128,2,2,0,1,0,0,0><<<GE128,256,0,stream>>>(ga);
  // m_new = (m + (X + act(y @ Wrb1))*c)*c -> B2
  if (use_mbf){
    ga = {}; ga.A=B1; ga.Bt=wt_rb1; ga.Out=B2; ga.Res1=B3; ga.Res2=mbf; ga.M=NE; ga.N=DE; ga.K=DE;
    gemm_k<128,128,2,2,0,4,0,0,0><<<GE128,256,0,stream>>>(ga);
  } else {
    ga = {}; ga.A=B1; ga.Bt=wt_rb1; ga.Out=B2; ga.Res1=B3; ga.Res2=m; ga.M=NE; ga.N=DE; ga.K=DE;
    gemm_k<128,128,2,2,0,4,0,0,1><<<GE128,256,0,stream>>>(ga);
  }
  // res_after[0]
  ga = {}; ga.A=B2; ga.Bt=wt_ra[0]; ga.Out=B1; ga.M=NE; ga.N=DE; ga.K=DE;
  gemm_k<128,128,2,2,0,1,0,0,0><<<GE128,256,0,stream>>>(ga);
  ga = {}; ga.A=B1; ga.Bt=wt_ra[1]; ga.Out=B0; ga.Res1=B2; ga.M=NE; ga.N=DE; ga.K=DE;
  gemm_k<128,128,2,2,0,3,0,0,0><<<GE128,256,0,stream>>>(ga);
  // res_after[1] -> final m_new in B2
  ga = {}; ga.A=B0; ga.Bt=wt_ra[2]; ga.Out=B1; ga.M=NE; ga.N=DE; ga.K=DE;
  gemm_k<128,128,2,2,0,1,0,0,0><<<GE128,256,0,stream>>>(ga);
  ga = {}; ga.A=B1; ga.Bt=wt_ra[3]; ga.Out=B2; ga.Res1=B0; ga.M=NE; ga.N=DE; ga.K=DE;
  gemm_k<128,128,2,2,0,3,0,0,0><<<GE128,256,0,stream>>>(ga);
  // segment sum (gather, CSR) fused with rbf_h MLP -> x2 (f32)
  gath_k<<<NA,256,0,stream>>>(B2, rbfh, wt_rbfh, csr_off, csr_edg, x2);
  // xa = act(x2 @ W_atom_dense) -> xa (f32)
  ga = {}; ga.A=x2; ga.Bt=wt_ad; ga.Out=xa; ga.M=NA; ga.N=DAH; ga.K=DE;
  gemm_k<128,64,4,1,1,1,1,0,0><<<GAT,256,0,stream>>>(ga);
  // atom residuals 0,1
  for (int i=0;i<2;i++){
    ga = {}; ga.A=xa; ga.Bt=wt_ar[2*i]; ga.Out=yb; ga.M=NA; ga.N=DAH; ga.K=DAH;
    gemm_k<128,64,4,1,1,1,1,0,0><<<GAT,256,0,stream>>>(ga);
    ga = {}; ga.A=yb; ga.Bt=wt_ar[2*i+1]; ga.Out=xa; ga.Res1=xa; ga.M=NA; ga.N=DAH; ga.K=DAH;
    gemm_k<128,64,4,1,1,3,1,1,0><<<GAT,256,0,stream>>>(ga);
  }
  // atom residual 2 fused with h_new = (h + xa')*c -> d_out
  ga = {}; ga.A=xa; ga.Bt=wt_ar[4]; ga.Out=yb; ga.M=NA; ga.N=DAH; ga.K=DAH;
  gemm_k<128,64,4,1,1,1,1,0,0><<<GAT,256,0,stream>>>(ga);
  ga = {}; ga.A=yb; ga.Bt=wt_ar[5]; ga.Out=out_h; ga.Res1=xa; ga.Res2=h; ga.M=NA; ga.N=DAH; ga.K=DAH;
  gemm_k<128,64,4,1,1,4,1,1,1><<<GAT,256,0,stream>>>(ga);
  // concat GEMM: mc = act([h_new[id_c]|h_new[id_a]|m_new] @ W_concat) -> B1
  ga = {}; ga.Bt=wt_cat; ga.Out=B1; ga.Hn=out_h; ga.Mn=B2; ga.idc=id_c; ga.ida=id_a;
  ga.M=NE; ga.N=DE; ga.K=2*DAH+DE;
  gemm_k<128,128,2,2,2,1,0,0,0><<<GE128,256,0,stream>>>(ga);
  // res_m: y = act(mc @ Wrm0) -> B0
  ga = {}; ga.A=B1; ga.Bt=wt_rm0; ga.Out=B0; ga.M=NE; ga.N=DE; ga.K=DE;
  gemm_k<128,128,2,2,0,1,0,0,0><<<GE128,256,0,stream>>>(ga);
  // m_out = (m_new + (mc + act(y @ Wrm1))*c)*c -> d_out
  ga = {}; ga.A=B0; ga.Bt=wt_rm1; ga.Out=out_m; ga.Res1=B1; ga.Res2=B2; ga.M=NE; ga.N=DE; ga.K=DE;
  gemm_k<128,128,2,2,0,4,1,0,0><<<GE128,256,0,stream>>>(ga);
}